// Round 3
// baseline (91.272 us; speedup 1.0000x reference)
//
#include <hip/hip_runtime.h>

#define BB 16
#define NN 4096
#define HQ (BB * NN)        // 65536 queries per direction
#define QT (2 * HQ)         // 131072 total
#define NSLICE 8
#define DBS (NN / NSLICE)   // 512 db points per block
#define WPTS (DBS / 4)      // 128 db points per wave
#define NGRP (WPTS / 4)     // 32 groups of 4 points
#define PQ 16               // queries per lane
#define QW (64 * PQ)        // 1024 queries per block (shared by all 4 waves)
#define NQC (NN / QW)       // 4 query chunks per batch
#define NGROUPS (QT / QW)   // 128 cross-slice reduce groups (1024 queries each)

typedef float v2f __attribute__((ext_vector_type(2)));

// Single fused kernel (R2 structure: sc1 agent-scope stores/loads for
// cross-block data, device atomicAdd arrival counters, NO threadfence).
//
// R3 main-loop changes (exact-arithmetic-preserving):
//  - v_min3_f32 (inline asm; no v_pk_min_f32 exists on CDNA, and clang
//    only folds fmin chains to min3 under nnan): 4 candidate distances
//    per group fold into ONE scalar acc with 2 min3 instead of 4 v_min.
//    8 -> 6 VALU inst per 4 pts per query. Min is exact & order-free.
//  - |t|^2 recomputed in-loop (pk_mul+pk_fma per group, amortized over
//    16 queries) instead of staged: 3 -> 2 ds_read_b128 per group
//    (-33% LDS traffic), sT2 staging dropped. Same fmaf(x,x,y*y)
//    rounding as before -> bit-identical distances.
// Per-SIMD per group-step: ~800 VALU-cyc vs 384 LDS-cyc (was 1024/576).
__global__ __launch_bounds__(256, 4) void chamfer_fused(
    const float* __restrict__ pred, const float* __restrict__ target,
    float* __restrict__ partial, float* __restrict__ bsum,
    int* __restrict__ cnt, float* __restrict__ out) {
  const int bid = blockIdx.x;
  const int slice = bid & (NSLICE - 1);
  const int qc = (bid >> 3) & (NQC - 1);
  const int b = (bid >> 5) & (BB - 1);
  const int dir = bid >> 9;
  const int grp = bid >> 3;  // reduce-group id, 0..127
  const int t = threadIdx.x;
  const int lane = t & 63;
  const int wid = t >> 6;

  // 16 KB: staging uses first 4 KB (2x512 floats); combine reuses all 16 KB.
  __shared__ float smem[4096];
  __shared__ int s_ord, s_ord2;
  __shared__ float red[4];
  float* sTX = smem;
  float* sTY = smem + DBS;

  // Stage 512 db points (opposite cloud), 2 per thread, SoA (X,Y only).
  const float2* __restrict__ dsrc = (const float2*)(dir ? pred : target);
  {
    const float4 two = ((const float4*)(dsrc + b * NN + slice * DBS))[t];
    ((float2*)sTX)[t] = {two.x, two.z};
    ((float2*)sTY)[t] = {two.y, two.w};
  }

  // Load this lane's 16 queries (same set for all 4 waves; L1-hot).
  const float2* __restrict__ qsrc = (const float2*)(dir ? target : pred);
  const int qbase = b * NN + qc * QW + lane;
  v2f nx[PQ], ny[PQ];
  float acc[PQ];
#pragma unroll
  for (int k = 0; k < PQ; ++k) {
    const float2 Q = qsrc[qbase + k * 64];
    const float fx = -2.0f * Q.x, fy = -2.0f * Q.y;
    nx[k] = {fx, fx};
    ny[k] = {fy, fy};
    acc[k] = 3.4e38f;
  }
  __syncthreads();

  const float4* __restrict__ gx = (const float4*)sTX + wid * (WPTS / 4);
  const float4* __restrict__ gy = (const float4*)sTY + wid * (WPTS / 4);
#pragma unroll 2
  for (int g = 0; g < NGRP; ++g) {
    const float4 x4 = gx[g], y4 = gy[g];
    const v2f xlo = {x4.x, x4.y}, xhi = {x4.z, x4.w};
    const v2f ylo = {y4.x, y4.y}, yhi = {y4.z, y4.w};
    // |t|^2 with the exact prologue rounding: fma(x,x, y*y).
    const v2f slo = __builtin_elementwise_fma(xlo, xlo, ylo * ylo);
    const v2f shi = __builtin_elementwise_fma(xhi, xhi, yhi * yhi);
#pragma unroll
    for (int k = 0; k < PQ; ++k) {
      v2f r0 = __builtin_elementwise_fma(ny[k], ylo, slo);
      r0 = __builtin_elementwise_fma(nx[k], xlo, r0);
      v2f r1 = __builtin_elementwise_fma(ny[k], yhi, shi);
      r1 = __builtin_elementwise_fma(nx[k], xhi, r1);
      // acc = min(acc, r0.x, r0.y); acc = min(acc, r1.x, r1.y)  (exact)
      asm("v_min3_f32 %0, %1, %2, %3"
          : "=v"(acc[k])
          : "v"(acc[k]), "v"(r0.x), "v"(r0.y));
      asm("v_min3_f32 %0, %1, %2, %3"
          : "=v"(acc[k])
          : "v"(acc[k]), "v"(r1.x), "v"(r1.y));
    }
  }

  __syncthreads();  // all waves done reading db before smem reuse
  // Per-lane mins -> cmb[k][wid][lane] (lane-contiguous: conflict-free).
#pragma unroll
  for (int k = 0; k < PQ; ++k) smem[(k * 4 + wid) * 64 + lane] = acc[k];
  __syncthreads();

  // Thread t combines the 4 wave-mins for queries k = wid*4 .. wid*4+3,
  // stores with agent-scope (sc1, write-through to LLC).
  const int pbase = slice * QT + dir * HQ + b * NN + qc * QW + lane;
#pragma unroll
  for (int j = 0; j < 4; ++j) {
    const int k = wid * 4 + j;
    const float m = fminf(fminf(smem[(k * 4 + 0) * 64 + lane],
                                smem[(k * 4 + 1) * 64 + lane]),
                          fminf(smem[(k * 4 + 2) * 64 + lane],
                                smem[(k * 4 + 3) * 64 + lane]));
    __hip_atomic_store(&partial[pbase + k * 64], m, __ATOMIC_RELAXED,
                       __HIP_MEMORY_SCOPE_AGENT);
  }

  // Release: barrier drains vmcnt(0) -> all sc1 stores are at LLC.
  __syncthreads();
  if (t == 0) s_ord = atomicAdd(&cnt[grp], 1);  // device-scope by default
  __syncthreads();
  if (s_ord != NSLICE - 1) return;  // 7 of 8 slice-blocks exit here

  // ---- last arriver: cross-slice min for this group's 1024 queries ----
  // Same fp tree as the verified chamfer_reduce (per-component fminf over
  // ascending s), but via sc1 scalar loads (L1/L2 may hold stale poison).
  const int i = grp * 256 + t;
  const int pidx = grp * QW + 4 * t;
  float mx = __hip_atomic_load(&partial[pidx + 0], __ATOMIC_RELAXED,
                               __HIP_MEMORY_SCOPE_AGENT);
  float my = __hip_atomic_load(&partial[pidx + 1], __ATOMIC_RELAXED,
                               __HIP_MEMORY_SCOPE_AGENT);
  float mz = __hip_atomic_load(&partial[pidx + 2], __ATOMIC_RELAXED,
                               __HIP_MEMORY_SCOPE_AGENT);
  float mw = __hip_atomic_load(&partial[pidx + 3], __ATOMIC_RELAXED,
                               __HIP_MEMORY_SCOPE_AGENT);
#pragma unroll
  for (int s = 1; s < NSLICE; ++s) {
    mx = fminf(mx, __hip_atomic_load(&partial[s * QT + pidx + 0],
                                     __ATOMIC_RELAXED,
                                     __HIP_MEMORY_SCOPE_AGENT));
    my = fminf(my, __hip_atomic_load(&partial[s * QT + pidx + 1],
                                     __ATOMIC_RELAXED,
                                     __HIP_MEMORY_SCOPE_AGENT));
    mz = fminf(mz, __hip_atomic_load(&partial[s * QT + pidx + 2],
                                     __ATOMIC_RELAXED,
                                     __HIP_MEMORY_SCOPE_AGENT));
    mw = fminf(mw, __hip_atomic_load(&partial[s * QT + pidx + 3],
                                     __ATOMIC_RELAXED,
                                     __HIP_MEMORY_SCOPE_AGENT));
  }
  const int rdir = i >= (HQ / 4);  // uniform per block
  const int q0 = i * 4 - rdir * HQ;
  const float2* __restrict__ rq = (const float2*)(rdir ? target : pred);
  const float2 Q0 = rq[q0], Q1 = rq[q0 + 1];
  const float2 Q2 = rq[q0 + 2], Q3 = rq[q0 + 3];
  float v = (mx + __builtin_fmaf(Q0.x, Q0.x, Q0.y * Q0.y)) +
            (my + __builtin_fmaf(Q1.x, Q1.x, Q1.y * Q1.y)) +
            (mz + __builtin_fmaf(Q2.x, Q2.x, Q2.y * Q2.y)) +
            (mw + __builtin_fmaf(Q3.x, Q3.x, Q3.y * Q3.y));
#pragma unroll
  for (int off = 32; off > 0; off >>= 1) v += __shfl_down(v, off, 64);
  if (lane == 0) red[wid] = v;
  __syncthreads();
  if (t == 0)
    __hip_atomic_store(&bsum[grp], (red[0] + red[1]) + (red[2] + red[3]),
                       __ATOMIC_RELAXED, __HIP_MEMORY_SCOPE_AGENT);

  // Release the bsum store (barrier drains t0's vmcnt), then signal.
  __syncthreads();
  if (t == 0) s_ord2 = atomicAdd(&cnt[NGROUPS], 1);
  __syncthreads();
  if (s_ord2 != NGROUPS - 1) return;  // 127 of 128 groups exit here

  if (t < 128) {  // verbatim old chamfer_final (wave0: dir0, wave1: dir1)
    float fv = __hip_atomic_load(&bsum[t], __ATOMIC_RELAXED,
                                 __HIP_MEMORY_SCOPE_AGENT);
#pragma unroll
    for (int off = 32; off > 0; off >>= 1) fv += __shfl_down(fv, off, 64);
    if ((t & 63) == 0) out[t >> 6] = fv * (1.0f / 65536.0f);
  }
}

extern "C" void kernel_launch(void* const* d_in, const int* in_sizes, int n_in,
                              void* d_out, int out_size, void* d_ws, size_t ws_size,
                              hipStream_t stream) {
  const float* pred = (const float*)d_in[0];
  const float* target = (const float*)d_in[1];
  float* out = (float*)d_out;
  float* partial = (float*)d_ws;  // 4 MiB
  float* bsum = (float*)((char*)d_ws + (size_t)NSLICE * QT * 4);  // 512 B
  int* cnt = (int*)((char*)d_ws + (size_t)NSLICE * QT * 4 + NGROUPS * 4);

  // ws is poisoned between iterations: zero the 129 arrival counters.
  // Async memset is stream-ordered and graph-capturable (no sync APIs).
  hipMemsetAsync(cnt, 0, (NGROUPS + 1) * sizeof(int), stream);
  chamfer_fused<<<2 * BB * NQC * NSLICE, 256, 0, stream>>>(pred, target,
                                                           partial, bsum, cnt,
                                                           out);
}